// Round 5
// baseline (6899.254 us; speedup 1.0000x reference)
//
#include <hip/hip_runtime.h>

#define SEQ   8192
#define HID   100
#define G4    400      // 4*HID gate rows
#define NCLS  20
#define CH    32       // steps per staged x_proj chunk
#define NCH   (SEQ / CH)

typedef float v2f __attribute__((ext_vector_type(2)));
typedef float v4f __attribute__((ext_vector_type(4)));

__device__ __forceinline__ float fast_sigmoid(float x) {
    return 1.0f / (1.0f + __expf(-x));
}
__device__ __forceinline__ float fast_tanh(float x) {
    float e = __expf(2.0f * x);          // saturates correctly at +/-inf
    return 1.0f - 2.0f / (e + 1.0f);
}

// Raw barrier: drains LDS ops only (lgkmcnt), NOT vmcnt — staged global
// loads stay in flight across step barriers.
__device__ __forceinline__ void wg_barrier() {
    asm volatile("s_waitcnt lgkmcnt(0)" ::: "memory");
    __builtin_amdgcn_s_barrier();
    asm volatile("" ::: "memory");
}

// 2-lane (pair) add via DPP quad_perm(1,0,3,2): lane 2k <-> 2k+1.
__device__ __forceinline__ float pair_add(float x) {
    int p = __builtin_amdgcn_update_dpp(0, __float_as_int(x), 0xB1, 0xF, 0xF, true);
    return x + __int_as_float(p);
}

// ---------------------------------------------------------------------------
// Kernel 1: x_proj[t][j] = dot(emb[seq[t]], W_ih[j]) + b_ih[j] + b_hh[j]
// Output PERMUTED: gate row j=c*100+r -> slot r*4+c, so scan thread for row r
// reads one v4f = {i,f,g,o} at xp[t*400 + 4r].
// ---------------------------------------------------------------------------
__global__ __launch_bounds__(512)
void xproj_kernel(const int* __restrict__ seq, const float* __restrict__ emb,
                  const float* __restrict__ Wih, const float* __restrict__ bih,
                  const float* __restrict__ bhh, float* __restrict__ xp)
{
    __shared__ float er[16][HID];
    const int tid = threadIdx.x;
    const int t0  = blockIdx.x * 16;

    if (tid < 400) {                       // 16 rows * 25 float4
        int r = tid / 25, q = tid - r * 25;
        int s = seq[t0 + r];
        *(float4*)&er[r][4 * q] = *(const float4*)&emb[(size_t)s * HID + 4 * q];
    }
    __syncthreads();

    const int row = (tid < G4) ? tid : (G4 - 1);
    const float4* wr = (const float4*)(Wih + (size_t)row * HID);
    const float bias = bih[row] + bhh[row];

    float acc[16];
    #pragma unroll
    for (int u = 0; u < 16; ++u) acc[u] = bias;

    #pragma unroll
    for (int k = 0; k < 25; ++k) {
        float4 wv = wr[k];
        #pragma unroll
        for (int u = 0; u < 16; ++u) {
            float4 ev = *(const float4*)&er[u][4 * k];
            acc[u] = fmaf(wv.x, ev.x, acc[u]);
            acc[u] = fmaf(wv.y, ev.y, acc[u]);
            acc[u] = fmaf(wv.z, ev.z, acc[u]);
            acc[u] = fmaf(wv.w, ev.w, acc[u]);
        }
    }
    if (tid < G4) {
        const int cj = row / HID, rj = row - cj * HID;
        const int pj = rj * 4 + cj;                        // permuted slot
        #pragma unroll
        for (int u = 0; u < 16; ++u)
            xp[(size_t)(t0 + u) * G4 + pj] = acc[u];
    }
}

// ---------------------------------------------------------------------------
// Kernel 2: persistent single-workgroup LSTM scan, 256 threads / 4 waves.
// Thread (r = tid>>1, s = tid&1): all 4 gate partial dots of h-row r over
// K-half s (s=0: quads 0..11, s=1: quads 12..24; uniform 13-iter loop with a
// zero-weight dummy for s=0). Pair-reduce = ONE DPP xor1 add.
//
// WHY 256 threads / waves_per_eu(1,1): R1-R4 all plateaued at ~1700 cy/step
// because weight "residency" silently became AGPR parking (VGPR_Count=104 <
// the 112 regs the pinned array needs; no scratch traffic) -> ~112
// v_accvgpr_read per thread per step. At 1 wave/EU the budget is 512 arch
// VGPRs; w[4][13]=208 + misc ~300 fits with slack -> true VGPR residency.
//
// x_proj staged into LDS in 32-step double-buffered chunks: zero global
// loads inside the step loop; chunk loads issued once per 32 steps stay in
// flight across the lgkm-only barriers.
// ---------------------------------------------------------------------------
template<int MODE>
__global__ __launch_bounds__(256)
__attribute__((amdgpu_waves_per_eu(1, 1)))
void lstm_scan(const float* xp,
               const float* __restrict__ Whh,
               const float* __restrict__ fcw, const float* __restrict__ fcb,
               const int* __restrict__ seq, const float* __restrict__ emb,
               const float* __restrict__ Wih, const float* __restrict__ bih,
               const float* __restrict__ bhh,
               float* __restrict__ out)
{
    __shared__ v4f h4[2][32];             // double-buffered h (100 of 128 used)
    __shared__ v4f xb[2][CH * HID];       // staged x_proj chunks (102400 B)
    __shared__ v4f er4[25];               // MODE1 only

    const int tid = threadIdx.x;
    const int s   = tid & 1;                        // K-half
    const int rg  = tid >> 1;                       // 0..127
    const int r   = (rg < HID) ? rg : (HID - 1);    // clamp idle threads
    const bool live = (rg < HID);

    // quad index for j-th slice element: s=0 -> j (j<12; j==12 dummy q=24),
    //                                    s=1 -> 12+j  (12..24)
    int qi[13];
    #pragma unroll
    for (int j = 0; j < 13; ++j)
        qi[j] = s ? (12 + j) : ((j < 12) ? j : 24);

    // W_hh slices for all 4 gate rows of row r: 208 VGPRs
    v4f w[4][13];
    #pragma unroll
    for (int c = 0; c < 4; ++c) {
        const float* wr = Whh + (size_t)(c * HID + r) * HID;
        #pragma unroll
        for (int j = 0; j < 13; ++j) {
            v4f t = *(const v4f*)(wr + 4 * qi[j]);
            if (s == 0 && j == 12) t = (v4f){0.f, 0.f, 0.f, 0.f};  // dummy
            w[c][j] = t;
        }
    }
    #pragma unroll
    for (int c = 0; c < 4; ++c)
        #pragma unroll
        for (int j = 0; j < 13; ++j)
            asm volatile("" : "+v"(w[c][j]));       // defeat remat

    v4f bias4 = {0.f, 0.f, 0.f, 0.f};
    if constexpr (MODE == 1) {
        #pragma unroll
        for (int c = 0; c < 4; ++c)
            ((float*)&bias4)[c] = bih[c * HID + r] + bhh[c * HID + r];
    }

    if (tid < 128) ((float*)h4)[tid] = 0.0f;        // zero h buffer 0
    float cst = 0.0f;

    if constexpr (MODE == 0) {                      // stage chunk 0
        const v4f* src = (const v4f*)xp;
        #pragma unroll
        for (int k = 0; k < 13; ++k) {
            int slot = tid + 256 * k;
            if (slot < CH * HID) xb[0][slot] = src[slot];
        }
    }
    __syncthreads();

    if constexpr (MODE == 0) {
        #pragma unroll 1
        for (int c = 0; c < NCH; ++c) {
            const int cur = c & 1;
            const bool more = (c + 1 < NCH);

            // issue next-chunk loads; consumed after the 32 steps below
            v4f g[13];
            if (more) {
                const v4f* src = (const v4f*)xp + (size_t)(c + 1) * (CH * HID);
                #pragma unroll
                for (int k = 0; k < 12; ++k) g[k] = src[tid + 256 * k];
                if (tid < CH * HID - 256 * 12)           // last 128 slots
                    g[12] = src[tid + 256 * 12];
            }

            const v4f* xrow = &xb[cur][r];
            #pragma unroll 1
            for (int u8 = 0; u8 < CH; u8 += 8) {
                #pragma unroll
                for (int v = 0; v < 8; ++v) {
                    // t = c*CH + u8 + v ; parity = v&1 (c*CH, u8 both even)
                    const v4f* hb = h4[v & 1];
                    v4f xpv = xrow[(u8 + v) * HID];

                    v2f a0 = {0.f,0.f}, a1 = {0.f,0.f};
                    v2f a2 = {0.f,0.f}, a3 = {0.f,0.f};
                    #pragma unroll
                    for (int j = 0; j < 13; ++j) {
                        v4f hv = hb[qi[j]];          // 2-addr broadcast read
                        a0 = __builtin_elementwise_fma(w[0][j].lo, hv.lo, a0);
                        a0 = __builtin_elementwise_fma(w[0][j].hi, hv.hi, a0);
                        a1 = __builtin_elementwise_fma(w[1][j].lo, hv.lo, a1);
                        a1 = __builtin_elementwise_fma(w[1][j].hi, hv.hi, a1);
                        a2 = __builtin_elementwise_fma(w[2][j].lo, hv.lo, a2);
                        a2 = __builtin_elementwise_fma(w[2][j].hi, hv.hi, a2);
                        a3 = __builtin_elementwise_fma(w[3][j].lo, hv.lo, a3);
                        a3 = __builtin_elementwise_fma(w[3][j].hi, hv.hi, a3);
                    }

                    float gi = pair_add(a0.x + a0.y) + xpv.x;
                    float gf = pair_add(a1.x + a1.y) + xpv.y;
                    float gg = pair_add(a2.x + a2.y) + xpv.z;
                    float go = pair_add(a3.x + a3.y) + xpv.w;

                    gi = fast_sigmoid(gi);
                    gf = fast_sigmoid(gf);
                    gg = fast_tanh(gg);
                    go = fast_sigmoid(go);

                    cst = fmaf(gf, cst, gi * gg);    // replicated x2 per pair
                    float hn = go * fast_tanh(cst);
                    if (live && s == 0)
                        ((float*)h4[(v & 1) ^ 1])[r] = hn;
                    wg_barrier();                     // ONE barrier/step
                }
            }

            if (more) {                               // write staged chunk
                #pragma unroll
                for (int k = 0; k < 12; ++k)
                    xb[cur ^ 1][tid + 256 * k] = g[k];
                if (tid < CH * HID - 256 * 12)
                    xb[cur ^ 1][tid + 256 * 12] = g[12];
                wg_barrier();
            }
        }
    } else {
        // MODE 1 (tiny workspace fallback): compute input projection inline
        // per step from global W_ih (L1-cached). Slow but correct.
        #pragma unroll 1
        for (int t = 0; t < SEQ; ++t) {
            if (tid < 25) {
                int sq = seq[t];
                er4[tid] = *(const v4f*)(emb + (size_t)sq * HID + 4 * tid);
            }
            wg_barrier();

            const v4f* hb = h4[t & 1];
            v2f a0 = {0.f,0.f}, a1 = {0.f,0.f}, a2 = {0.f,0.f}, a3 = {0.f,0.f};
            #pragma unroll
            for (int j = 0; j < 13; ++j) {
                v4f hv = hb[qi[j]];
                v4f ev = er4[qi[j]];
                #pragma unroll
                for (int c = 0; c < 4; ++c) {
                    v4f wq = *(const v4f*)(Wih + (size_t)(c * HID + r) * HID + 4 * qi[j]);
                    if (s == 0 && j == 12) wq = (v4f){0.f, 0.f, 0.f, 0.f};
                    v2f* ac = (c == 0) ? &a0 : (c == 1) ? &a1 : (c == 2) ? &a2 : &a3;
                    *ac = __builtin_elementwise_fma(w[c][j].lo, hv.lo, *ac);
                    *ac = __builtin_elementwise_fma(w[c][j].hi, hv.hi, *ac);
                    *ac = __builtin_elementwise_fma(wq.lo, ev.lo, *ac);
                    *ac = __builtin_elementwise_fma(wq.hi, ev.hi, *ac);
                }
            }

            float gi = pair_add(a0.x + a0.y) + ((float*)&bias4)[0];
            float gf = pair_add(a1.x + a1.y) + ((float*)&bias4)[1];
            float gg = pair_add(a2.x + a2.y) + ((float*)&bias4)[2];
            float go = pair_add(a3.x + a3.y) + ((float*)&bias4)[3];

            gi = fast_sigmoid(gi);
            gf = fast_sigmoid(gf);
            gg = fast_tanh(gg);
            go = fast_sigmoid(go);

            cst = fmaf(gf, cst, gi * gg);
            float hn = go * fast_tanh(cst);
            if (live && s == 0)
                ((float*)h4[(t & 1) ^ 1])[r] = hn;
            wg_barrier();
        }
    }

    // final FC: out[20] = fc_w @ h_last + fc_b  (SEQ even -> h_last in h4[0])
    if (tid < NCLS) {
        const float* hf = (const float*)h4[0];
        const float* fr = fcw + (size_t)tid * HID;
        float acc = fcb[tid];
        #pragma unroll
        for (int k = 0; k < HID; ++k) acc = fmaf(fr[k], hf[k], acc);
        out[tid] = acc;
    }
}

// ---------------------------------------------------------------------------
extern "C" void kernel_launch(void* const* d_in, const int* in_sizes, int n_in,
                              void* d_out, int out_size, void* d_ws, size_t ws_size,
                              hipStream_t stream)
{
    const int*   seq = (const int*)d_in[0];
    const float* emb = (const float*)d_in[1];
    const float* Wih = (const float*)d_in[2];
    const float* Whh = (const float*)d_in[3];
    const float* bih = (const float*)d_in[4];
    const float* bhh = (const float*)d_in[5];
    const float* fcw = (const float*)d_in[6];
    const float* fcb = (const float*)d_in[7];
    float* out = (float*)d_out;
    float* xp  = (float*)d_ws;

    const size_t need = (size_t)SEQ * G4 * sizeof(float);
    if (ws_size >= need) {
        xproj_kernel<<<SEQ / 16, 512, 0, stream>>>(seq, emb, Wih, bih, bhh, xp);
        lstm_scan<0><<<1, 256, 0, stream>>>(xp, Whh, fcw, fcb,
                                            seq, emb, Wih, bih, bhh, out);
    } else {
        lstm_scan<1><<<1, 256, 0, stream>>>(nullptr, Whh, fcw, fcb,
                                            seq, emb, Wih, bih, bhh, out);
    }
}